// Round 6
// baseline (18526.541 us; speedup 1.0000x reference)
//
#include <hip/hip_runtime.h>
#include <hip/hip_cooperative_groups.h>

namespace cg = cooperative_groups;

#define VOCAB   32000
#define DIM     512
#define HDIM    512
#define BATCH   32
#define TSTEPS  128
#define TOPKN   5
#define CAND    8
#define BOSTOK  1
#define ALPHA   0.2f
#define G3H     1536

#define NBLK    256
#define NTHR    256
#define GEMMBLK 250
#define CPB     128

typedef unsigned long long u64;
typedef __bf16 bf16x8 __attribute__((ext_vector_type(8)));
typedef float  f32x4  __attribute__((ext_vector_type(4)));

// ---------------- shared helpers ----------------
__device__ __forceinline__ bool better(float v1, int i1, float v2, int i2) {
    return (v1 > v2) || (v1 == v2 && i1 < i2);   // value desc, index asc
}

__device__ __forceinline__ void ins5(float (&lv)[TOPKN], int (&li)[TOPKN], float v, int i) {
    if (better(v, i, lv[4], li[4])) {
        lv[4] = v; li[4] = i;
#pragma unroll
        for (int q = 4; q > 0; --q) {
            if (better(lv[q], li[q], lv[q - 1], li[q - 1])) {
                float tv = lv[q]; lv[q] = lv[q - 1]; lv[q - 1] = tv;
                int   ti = li[q]; li[q] = li[q - 1]; li[q - 1] = ti;
            }
        }
    }
}

__device__ __forceinline__ void ins8(float (&lv)[CAND], int (&li)[CAND], float v, int i) {
    if (better(v, i, lv[CAND - 1], li[CAND - 1])) {
        lv[CAND - 1] = v; li[CAND - 1] = i;
#pragma unroll
        for (int q = CAND - 1; q > 0; --q) {
            if (better(lv[q], li[q], lv[q - 1], li[q - 1])) {
                float tv = lv[q]; lv[q] = lv[q - 1]; lv[q - 1] = tv;
                int   ti = li[q]; li[q] = li[q - 1]; li[q - 1] = ti;
            }
        }
    }
}

__device__ __forceinline__ unsigned f2bf(float f) {   // f32 -> bf16 RNE
    unsigned u = __float_as_uint(f);
    return (u + 0x7FFFu + ((u >> 16) & 1u)) >> 16;
}

// ---- agent-scope (MALL-coherent) atomics for cross-block mutable state ----
__device__ __forceinline__ u64 aldu64(const u64* p) {
    return __hip_atomic_load(p, __ATOMIC_RELAXED, __HIP_MEMORY_SCOPE_AGENT);
}
__device__ __forceinline__ void astu64(u64* p, u64 v) {
    __hip_atomic_store(p, v, __ATOMIC_RELAXED, __HIP_MEMORY_SCOPE_AGENT);
}
__device__ __forceinline__ float aldf(const float* p) {
    return __hip_atomic_load(p, __ATOMIC_RELAXED, __HIP_MEMORY_SCOPE_AGENT);
}
__device__ __forceinline__ void astf(float* p, float v) {
    __hip_atomic_store(p, v, __ATOMIC_RELAXED, __HIP_MEMORY_SCOPE_AGENT);
}
__device__ __forceinline__ unsigned aldu32(const unsigned* p) {
    return __hip_atomic_load(p, __ATOMIC_RELAXED, __HIP_MEMORY_SCOPE_AGENT);
}

// directed counting edges: producers fetch_add after vmcnt drain; consumers poll.
__device__ __forceinline__ void signal_edge(unsigned* c, int tid) {
    asm volatile("s_waitcnt vmcnt(0) lgkmcnt(0)" ::: "memory");
    __syncthreads();
    if (tid == 0)
        __hip_atomic_fetch_add(c, 1u, __ATOMIC_RELAXED, __HIP_MEMORY_SCOPE_AGENT);
}
__device__ __forceinline__ void wait_edge(const unsigned* c, unsigned target, int tid) {
    if (tid == 0) {
        unsigned v = aldu32(c);
        long g = 0;
        while (v < target && g < 2000000L) {   // bounded: ~0.5 s worst case, no hang
            __builtin_amdgcn_s_sleep(1);
            v = aldu32(c);
            ++g;
        }
    }
    __syncthreads();
}

// =====================================================================
// ========================== round-6 path =============================
// =====================================================================

struct L6 {
    union {
        float protile[64][129];               // prologue scratch
        struct {                              // GEMM phase
            u64      h2r[BATCH][256];         // raw h2 (f32 pairs)   64 KB
            unsigned hbf[BATCH][256];         // bf16-packed, XOR-swz 32 KB
            float pwv[4][BATCH][TOPKN];
            int   pwi[4][BATCH][TOPKN];
        } g;
        struct {                              // GATE phase (blocks 0..31)
            float erow[BATCH][516];           // leaky(E[sel]) rows   66 KB
            float xgs[BATCH][48];             // xg slices
            int   sel[BATCH];
        } b;
        struct {                              // SEL phase (blocks 0..31)
            u64   m8[4][CAND];
            int   c8[CAND];
            float e8[CAND];
        } s;
    };
};

__device__ void prologue6(L6& s, int j, int tid,
    const float* __restrict__ Wo, const float* __restrict__ U,
    const float* __restrict__ Wx,
    unsigned* __restrict__ WoPk, float* __restrict__ WoT,
    float* __restrict__ UT, float* __restrict__ WxT)
{
    for (int i = tid; i < 6 * DIM; i += NTHR) {   // U_T / Wx_T rows (6 gate-cols)
        const int rr = i >> 9, k = i & 511;
        const int gc = (rr >> 1) * HDIM + 2 * j + (rr & 1);
        UT[(size_t)gc * DIM + k]  = U[(size_t)k * G3H + gc];
        WxT[(size_t)gc * DIM + k] = Wx[(size_t)k * G3H + gc];
    }
    if (j < GEMMBLK) {
        for (int chunk = 0; chunk < 8; ++chunk) {
            const int k0 = chunk * 64;
            __syncthreads();
#pragma unroll
            for (int it = 0; it < 8; ++it) {      // coalesced f32 tile [64][128]
                const int idx = tid + it * NTHR;
                const int kk = idx >> 5, c4 = (idx & 31) << 2;
                const float4 v = *(const float4*)(Wo + (size_t)(k0 + kk) * VOCAB + j * CPB + c4);
                s.protile[kk][c4] = v.x; s.protile[kk][c4 + 1] = v.y;
                s.protile[kk][c4 + 2] = v.z; s.protile[kk][c4 + 3] = v.w;
            }
            __syncthreads();
            {   // Wo_T f32 (exact, for SEL rescore)
                const int kh = tid >> 7, c = tid & 127;
                float* dst = WoT + ((size_t)j * CPB + c) * DIM + k0 + kh * 32;
#pragma unroll
                for (int kk = 0; kk < 32; ++kk) dst[kk] = s.protile[kh * 32 + kk][c];
            }
            // Wo packed bf16 in MFMA B-frag order (proven r3-r5)
#pragma unroll
            for (int uu = 0; uu < 4; ++uu) {
                const int u = tid + uu * NTHR;
                const int kss = u >> 9, nt = (u >> 6) & 7, ll = u & 63;
                const int kb = kss * 32 + ((ll >> 4) << 3);
                const int c  = nt * 16 + (ll & 15);
                unsigned d[4];
#pragma unroll
                for (int e2 = 0; e2 < 4; ++e2) {
                    const unsigned lo = f2bf(s.protile[kb + 2 * e2][c]);
                    const unsigned hi = f2bf(s.protile[kb + 2 * e2 + 1][c]);
                    d[e2] = lo | (hi << 16);
                }
                const int ksg = chunk * 2 + kss;
                uint4* dst = (uint4*)WoPk + ((((size_t)j * 16 + ksg) * 8 + nt) * 64 + ll);
                *dst = *(const uint4*)d;
            }
        }
    }
}

// hg_0 slice for gate block g (48 gate-cols x 32 batches) from ctx. Local-use only.
__device__ void hg0_slice(int g, int tid, const float* __restrict__ ctx,
                          const float* __restrict__ UT, const float* __restrict__ b_r,
                          float* __restrict__ hg)
{
    const int b = tid & 31, base = tid >> 5;
    float acc[6]; const float4* up[6]; int gcs[6];
#pragma unroll
    for (int d = 0; d < 6; ++d) {
        const int sub = base + 8 * d;
        const int gc = (sub >> 4) * HDIM + 16 * g + (sub & 15);
        gcs[d] = gc; acc[d] = b_r[gc];
        up[d] = (const float4*)(UT + (size_t)gc * DIM);
    }
    const float4* cp = (const float4*)(ctx + (size_t)b * HDIM);
    for (int i = 0; i < 128; ++i) {
        const float4 c4 = cp[i];
#pragma unroll
        for (int d = 0; d < 6; ++d) {
            const float4 u4 = up[d][i];
            acc[d] = fmaf(c4.x, u4.x, fmaf(c4.y, u4.y, fmaf(c4.z, u4.z, fmaf(c4.w, u4.w, acc[d]))));
        }
    }
#pragma unroll
    for (int d = 0; d < 6; ++d) astf(&hg[(size_t)b * G3H + gcs[d]], acc[d]);
}

// GATE phase: sel -> E-stage -> xg dots -> GRU -> publish h2_t (block g: hcols 16g..16g+16)
__device__ void gate_phase(L6& s, int g, int tid, int t,
    const float* __restrict__ E, const float* __restrict__ WxT,
    const float* __restrict__ b_i, const float* __restrict__ ctx,
    const unsigned* __restrict__ selw, const float* __restrict__ hg,
    const u64* __restrict__ h2prev, u64* __restrict__ h2cur)
{
    if (tid < BATCH)
        s.b.sel[tid] = (t == 0) ? BOSTOK : (int)aldu32(&selw[tid]);
    __syncthreads();
    {   // stage leaky(E[sel[b]]) rows: 8 threads x 16 float4 per row
        const int b = tid >> 3, ch = tid & 7;
        const float4* src = (const float4*)(E + (size_t)s.b.sel[b] * DIM) + ch * 16;
        float* dst = &s.b.erow[b][ch * 64];
#pragma unroll
        for (int i = 0; i < 16; ++i) {
            float4 v = src[i];
            v.x = v.x > 0.f ? v.x : ALPHA * v.x;
            v.y = v.y > 0.f ? v.y : ALPHA * v.y;
            v.z = v.z > 0.f ? v.z : ALPHA * v.z;
            v.w = v.w > 0.f ? v.w : ALPHA * v.w;
            *(float4*)(dst + 4 * i) = v;
        }
    }
    __syncthreads();
    // xg dots: thread (b = tid&31, base = tid>>5) does 6 gate-cols sharing one E row
    const int b = tid & 31, base = tid >> 5;
    {
        float acc[6]; const float4* wxp[6]; int subs[6];
#pragma unroll
        for (int d = 0; d < 6; ++d) {
            const int sub = base + 8 * d;
            const int gc = (sub >> 4) * HDIM + 16 * g + (sub & 15);
            subs[d] = sub; acc[d] = b_i[gc];
            wxp[d] = (const float4*)(WxT + (size_t)gc * DIM);
        }
        const float4* er = (const float4*)&s.b.erow[b][0];
        for (int i = 0; i < 128; ++i) {
            const float4 e4 = er[i];
#pragma unroll
            for (int d = 0; d < 6; ++d) {
                const float4 w4 = wxp[d][i];
                acc[d] = fmaf(e4.x, w4.x, fmaf(e4.y, w4.y, fmaf(e4.z, w4.z, fmaf(e4.w, w4.w, acc[d]))));
            }
        }
#pragma unroll
        for (int d = 0; d < 6; ++d) s.b.xgs[b][subs[d]] = acc[d];
    }
    __syncthreads();
    {   // GRU update: thread (bb = tid&31, jj = tid>>5) -> hcols {16g+2jj, +1}
        const int bb = tid & 31, jj = tid >> 5;
        const int hc0 = 16 * g + 2 * jj;
        float hold0, hold1;
        if (t == 0) {
            hold0 = ctx[(size_t)bb * HDIM + hc0];
            hold1 = ctx[(size_t)bb * HDIM + hc0 + 1];
        } else {
            const u64 hv = aldu64(&h2prev[bb * 256 + 8 * g + jj]);
            hold0 = __uint_as_float((unsigned)hv);
            hold1 = __uint_as_float((unsigned)(hv >> 32));
        }
        float nh[2];
#pragma unroll
        for (int q = 0; q < 2; ++q) {
            const int c = 2 * jj + q, hc = hc0 + q;
            const float xz = s.b.xgs[bb][c], xr = s.b.xgs[bb][16 + c], xh = s.b.xgs[bb][32 + c];
            const float hz  = aldf(&hg[(size_t)bb * G3H + hc]);
            const float hr_ = aldf(&hg[(size_t)bb * G3H + HDIM + hc]);
            const float hh  = aldf(&hg[(size_t)bb * G3H + 2 * HDIM + hc]);
            const float z  = 1.f / (1.f + expf(-(xz + hz)));
            const float r  = 1.f / (1.f + expf(-(xr + hr_)));
            const float cd = tanhf(xh + r * hh);
            nh[q] = z * (q ? hold1 : hold0) + (1.f - z) * cd;
        }
        astu64(&h2cur[bb * 256 + 8 * g + jj],
               ((u64)__float_as_uint(nh[1]) << 32) | __float_as_uint(nh[0]));
    }
}

// SEL phase (block b): merge pvx[b] -> top8 -> exact rescore -> sel for step tsel
__device__ void sel_phase(L6& s, int b, int tid, int tsel,
    const float* __restrict__ WoT, const float* __restrict__ bo,
    const int* __restrict__ rix, const u64* __restrict__ h2in,
    const u64* __restrict__ pvx, unsigned* __restrict__ selw)
{
    float lv[TOPKN]; int li[TOPKN];
#pragma unroll
    for (int q = 0; q < TOPKN; ++q) { lv[q] = -INFINITY; li[q] = 0x7fffffff; }
    const u64* pb = &pvx[(size_t)b * (GEMMBLK * TOPKN)];
    for (int e = tid; e < GEMMBLK * TOPKN; e += NTHR) {
        const u64 v = aldu64(pb + e);
        ins5(lv, li, __uint_as_float((unsigned)(v >> 32)), (int)(unsigned)v);
    }
    float v8[CAND]; int i8[CAND];
#pragma unroll
    for (int q = 0; q < CAND; ++q) {
        v8[q] = (q < TOPKN) ? lv[q] : -INFINITY;
        i8[q] = (q < TOPKN) ? li[q] : 0x7fffffff;
    }
#pragma unroll
    for (int m = 1; m < 64; m <<= 1) {
#pragma unroll
        for (int q = 0; q < CAND; ++q) {
            const float ov = __shfl_xor(v8[q], m);
            const int   oi = __shfl_xor(i8[q], m);
            ins8(v8, i8, ov, oi);
        }
    }
    if ((tid & 63) == 0) {
#pragma unroll
        for (int q = 0; q < CAND; ++q)
            s.s.m8[tid >> 6][q] = ((u64)__float_as_uint(v8[q]) << 32) | (unsigned)i8[q];
    }
    __syncthreads();
    if (tid == 0) {
        float f8[CAND]; int fi[CAND];
#pragma unroll
        for (int q = 0; q < CAND; ++q) { f8[q] = -INFINITY; fi[q] = 0x7fffffff; }
#pragma unroll
        for (int w2 = 0; w2 < 4; ++w2)
#pragma unroll
            for (int q = 0; q < CAND; ++q) {
                const u64 v = s.s.m8[w2][q];
                ins8(f8, fi, __uint_as_float((unsigned)(v >> 32)), (int)(unsigned)v);
            }
#pragma unroll
        for (int q = 0; q < CAND; ++q) s.s.c8[q] = fi[q];
    }
    __syncthreads();
    {   // exact rescore: 8 groups x 32 lanes, coalesced WoT rows
        const int gp = tid >> 5, sub = tid & 31;
        const int cnd = s.s.c8[gp];
        const float4* wp = (const float4*)(WoT + (size_t)cnd * DIM) + sub * 4;
        const u64* hp = &h2in[(size_t)b * 256 + sub * 8];
        float a = 0.f;
#pragma unroll
        for (int ii = 0; ii < 4; ++ii) {
            const float4 wv = wp[ii];
            const u64 hA = aldu64(hp + 2 * ii);
            const u64 hB = aldu64(hp + 2 * ii + 1);
            a = fmaf(__uint_as_float((unsigned)hA), wv.x,
                fmaf(__uint_as_float((unsigned)(hA >> 32)), wv.y,
                fmaf(__uint_as_float((unsigned)hB), wv.z,
                fmaf(__uint_as_float((unsigned)(hB >> 32)), wv.w, a))));
        }
#pragma unroll
        for (int m = 1; m < 32; m <<= 1) a += __shfl_xor(a, m);
        if (sub == 0) s.s.e8[gp] = a + bo[cnd];
    }
    __syncthreads();
    if (tid == 0) {
        float lv5[TOPKN]; int li5[TOPKN];
#pragma unroll
        for (int q = 0; q < TOPKN; ++q) { lv5[q] = -INFINITY; li5[q] = 0x7fffffff; }
#pragma unroll
        for (int q = 0; q < CAND; ++q) ins5(lv5, li5, s.s.e8[q], s.s.c8[q]);
        const int ridx = rix[(tsel - 1) * BATCH + b];
        int sb = li5[0];
#pragma unroll
        for (int q = 1; q < TOPKN; ++q) if (ridx == q) sb = li5[q];
        __hip_atomic_store(&selw[b], (unsigned)sb, __ATOMIC_RELAXED, __HIP_MEMORY_SCOPE_AGENT);
    }
}

// GEMM phase: stage h2 (raw + swz bf16), MFMA GEMM, topk partials, hg_{t+1} (round-5 proven)
__device__ void gemm_phase(L6& s, int j, int tid, int t,
    const unsigned* __restrict__ WoPk, const float* __restrict__ bo,
    const float* __restrict__ UT, const float* __restrict__ b_r,
    const u64* __restrict__ h2in, float* __restrict__ out,
    float* __restrict__ hg, u64* __restrict__ pvx)
{
#pragma unroll 4
    for (int q = 0; q < BATCH; ++q) {
        const u64 v = aldu64(&h2in[q * 256 + tid]);
        s.g.h2r[q][tid] = v;
        const float lo = __uint_as_float((unsigned)v);
        const float hi = __uint_as_float((unsigned)(v >> 32));
        s.g.hbf[q][tid ^ ((q & 7) << 2)] = f2bf(lo) | (f2bf(hi) << 16);  // XOR-swz
    }
    __syncthreads();
    const int w = tid >> 6, l = tid & 63;
    if (j < GEMMBLK) {
        f32x4 acc[2][2];
        acc[0][0] = {0.f,0.f,0.f,0.f}; acc[0][1] = {0.f,0.f,0.f,0.f};
        acc[1][0] = {0.f,0.f,0.f,0.f}; acc[1][1] = {0.f,0.f,0.f,0.f};
        const uint4* wpk = (const uint4*)WoPk;
        const size_t base = (size_t)j * 8192 + l;
        const int r0 = l & 15, r1 = 16 + (l & 15);
        const int ko = (l >> 4) << 2;
        const int swz = (r0 & 7) << 2;
        uint4 vb[8];
#pragma unroll
        for (int pf = 0; pf < 4; ++pf) {
            vb[2*pf]   = wpk[base + (size_t)(pf * 8 + 2 * w)     * 64];
            vb[2*pf+1] = wpk[base + (size_t)(pf * 8 + 2 * w + 1) * 64];
        }
#pragma unroll
        for (int ks = 0; ks < 16; ++ks) {
            const int sl2 = (ks & 3) * 2;
            const uint4 b0 = vb[sl2], b1 = vb[sl2 + 1];
            const uint4 a0 = *(const uint4*)&s.g.hbf[r0][(ks * 16 + ko) ^ swz];
            const uint4 a1 = *(const uint4*)&s.g.hbf[r1][(ks * 16 + ko) ^ swz];
            if (ks < 12) {
                vb[sl2]     = wpk[base + (size_t)((ks + 4) * 8 + 2 * w)     * 64];
                vb[sl2 + 1] = wpk[base + (size_t)((ks + 4) * 8 + 2 * w + 1) * 64];
            }
            const bf16x8 A0 = __builtin_bit_cast(bf16x8, a0);
            const bf16x8 A1 = __builtin_bit_cast(bf16x8, a1);
            const bf16x8 B0 = __builtin_bit_cast(bf16x8, b0);
            const bf16x8 B1 = __builtin_bit_cast(bf16x8, b1);
            acc[0][0] = __builtin_amdgcn_mfma_f32_16x16x32_bf16(A0, B0, acc[0][0], 0, 0, 0);
            acc[0][1] = __builtin_amdgcn_mfma_f32_16x16x32_bf16(A0, B1, acc[0][1], 0, 0, 0);
            acc[1][0] = __builtin_amdgcn_mfma_f32_16x16x32_bf16(A1, B0, acc[1][0], 0, 0, 0);
            acc[1][1] = __builtin_amdgcn_mfma_f32_16x16x32_bf16(A1, B1, acc[1][1], 0, 0, 0);
        }
        const int c0 = j * CPB + (2 * w) * 16 + (l & 15);
        const int c1 = j * CPB + (2 * w + 1) * 16 + (l & 15);
        const float bo0 = bo[c0], bo1 = bo[c1];
#pragma unroll
        for (int m = 0; m < 2; ++m) {
#pragma unroll
            for (int r = 0; r < 4; ++r) {
                const int b = 16 * m + ((l >> 4) << 2) + r;
                const float v0 = acc[m][0][r] + bo0;
                const float v1 = acc[m][1][r] + bo1;
                __builtin_nontemporal_store(v0, out + ((size_t)b * TSTEPS + t) * VOCAB + c0);
                __builtin_nontemporal_store(v1, out + ((size_t)b * TSTEPS + t) * VOCAB + c1);
                float lv[TOPKN]; int li[TOPKN];
#pragma unroll
                for (int q = 0; q < TOPKN; ++q) { lv[q] = -INFINITY; li[q] = 0x7fffffff; }
                ins5(lv, li, v0, c0);
                ins5(lv, li, v1, c1);
#pragma unroll
                for (int mask = 1; mask < 16; mask <<= 1) {
                    float ov[TOPKN]; int oi[TOPKN];
#pragma unroll
                    for (int q = 0; q < TOPKN; ++q) {
                        ov[q] = __shfl_xor(lv[q], mask);
                        oi[q] = __shfl_xor(li[q], mask);
                    }
#pragma unroll
                    for (int q = 0; q < TOPKN; ++q) ins5(lv, li, ov[q], oi[q]);
                }
                if ((l & 15) == 0) {
#pragma unroll
                    for (int q = 0; q < TOPKN; ++q) { s.g.pwv[w][b][q] = lv[q]; s.g.pwi[w][b][q] = li[q]; }
                }
            }
        }
    }
    // hg_{t+1} from LDS-staged h2 (broadcast reads, per-lane UT rows)
    if (tid < 192) {
        const int g  = j * 192 + tid;
        const int bb = j >> 3;
        const int c  = 192 * (j & 7) + tid;
        const u64* hr = s.g.h2r[bb];
        const float4* up = (const float4*)(UT + (size_t)c * DIM);
        float a0 = b_r[c], a1 = 0.f;
#pragma unroll 4
        for (int i = 0; i < 128; i += 2) {
            const float4 u0 = up[i];
            const float2 hA = __builtin_bit_cast(float2, hr[2 * i]);
            const float2 hB = __builtin_bit_cast(float2, hr[2 * i + 1]);
            const float4 u1 = up[i + 1];
            const float2 hC = __builtin_bit_cast(float2, hr[2 * i + 2]);
            const float2 hD = __builtin_bit_cast(float2, hr[2 * i + 3]);
            a0 = fmaf(hA.x, u0.x, fmaf(hA.y, u0.y, fmaf(hB.x, u0.z, fmaf(hB.y, u0.w, a0))));
            a1 = fmaf(hC.x, u1.x, fmaf(hC.y, u1.y, fmaf(hD.x, u1.z, fmaf(hD.y, u1.w, a1))));
        }
        astf(&hg[g], a0 + a1);
    }
    __syncthreads();
    if (j < GEMMBLK && tid < BATCH) {
        float lv[TOPKN]; int li[TOPKN];
#pragma unroll
        for (int q = 0; q < TOPKN; ++q) { lv[q] = -INFINITY; li[q] = 0x7fffffff; }
#pragma unroll
        for (int w4 = 0; w4 < 4; ++w4)
#pragma unroll
            for (int q = 0; q < TOPKN; ++q) ins5(lv, li, s.g.pwv[w4][tid][q], s.g.pwi[w4][tid][q]);
        const size_t base = ((size_t)tid * GEMMBLK + j) * TOPKN;
#pragma unroll
        for (int q = 0; q < TOPKN; ++q)
            astu64(&pvx[base + q], ((u64)__float_as_uint(lv[q]) << 32) | (unsigned)li[q]);
    }
}

static __global__ void __launch_bounds__(NTHR, 1)
gru6(const float* __restrict__ E,  const float* __restrict__ Wx,
     const float* __restrict__ U,  const float* __restrict__ b_i,
     const float* __restrict__ b_r, const float* __restrict__ Wo,
     const float* __restrict__ bo, const float* __restrict__ ctx,
     const int* __restrict__ rix,  float* __restrict__ out,
     unsigned* __restrict__ WoPk,  float* __restrict__ WoT,
     float* __restrict__ UT,       float* __restrict__ WxT,
     u64* __restrict__ h2x,        float* __restrict__ hg,
     u64* __restrict__ pvx,        unsigned* __restrict__ bar,
     unsigned* __restrict__ selw)
{
    cg::grid_group grid = cg::this_grid();
    extern __shared__ char smem_raw[];
    L6& s = *(L6*)smem_raw;
    const int j = blockIdx.x, tid = threadIdx.x;
    unsigned* h2c = bar + 0;
    unsigned* pvc = bar + 32;
    unsigned* slc = bar + 64;

    prologue6(s, j, tid, Wo, U, Wx, WoPk, WoT, UT, WxT);
    grid.sync();                       // heavy sync once: publish RO arrays
    if (j < 32) hg0_slice(j, tid, ctx, UT, b_r, hg);   // own-slice, self-consumed

    for (int t = 0; t < TSTEPS; ++t) {
        u64*       h2cur  = h2x + (t & 1) * 8192;
        const u64* h2prev = h2x + ((t & 1) ^ 1) * 8192;
        if (j < 32) {
            if (t > 0) wait_edge(slc, 32u * (unsigned)t, tid);
            gate_phase(s, j, tid, t, E, WxT, b_i, ctx, selw, hg, h2prev, h2cur);
            signal_edge(h2c, tid);
        }
        wait_edge(h2c, 32u * (unsigned)(t + 1), tid);
        gemm_phase(s, j, tid, t, WoPk, bo, UT, b_r, h2cur, out, hg, pvx);
        signal_edge(pvc, tid);
        if (t < TSTEPS - 1 && j < 32) {
            wait_edge(pvc, 256u * (unsigned)(t + 1), tid);
            sel_phase(s, j, tid, t + 1, WoT, bo, rix, h2cur, pvx, selw);
            signal_edge(slc, tid);
        }
    }
}

// =====================================================================
// ================= round-2 f32 fallback (proven) =====================
// =====================================================================

#define KH      256
#define H2LD    (KH + 1)

struct alignas(16) SMem {
    float h2h[BATCH][H2LD];
    float sx[DIM];
    float dd[3][64];
    float mbv[4][BATCH][TOPKN];
    int   mbi[4][BATCH][TOPKN];
    float mrgv[4];
    int   mrgi[4];
    int   mrgt[4];
};

__device__ __forceinline__ float dot256(const float* __restrict__ M, const float* sv,
                                        int c, int kb, float acc) {
    const float* p = M + (size_t)kb * G3H + c;
    float wa[32], wb[32];
#pragma unroll
    for (int u = 0; u < 32; ++u) wa[u] = p[(size_t)u * G3H];
    for (int k0 = 0; k0 < KH; k0 += 64) {
#pragma unroll
        for (int u = 0; u < 32; ++u) wb[u] = p[(size_t)(k0 + 32 + u) * G3H];
#pragma unroll
        for (int u = 0; u < 32; ++u) acc = fmaf(sv[k0 + u], wa[u], acc);
        if (k0 + 64 < KH) {
#pragma unroll
            for (int u = 0; u < 32; ++u) wa[u] = p[(size_t)(k0 + 64 + u) * G3H];
        }
#pragma unroll
        for (int u = 0; u < 32; ++u) acc = fmaf(sv[k0 + 32 + u], wb[u], acc);
    }
    return acc;
}

__device__ __forceinline__ void stage_half(SMem& s, const float* __restrict__ src,
                                           int kb, int tid) {
#pragma unroll
    for (int it = 0; it < 8; ++it) {
        const int i  = tid + it * NTHR;
        const int bb = i >> 6;
        const int k4 = i & 63;
        const float4 v = *(const float4*)(src + (size_t)bb * DIM + kb + k4 * 4);
        float* d = &s.h2h[bb][k4 * 4];
        d[0] = v.x; d[1] = v.y; d[2] = v.z; d[3] = v.w;
    }
}

__device__ __forceinline__ void loadg(float4 (&wv)[8], float (&av)[8][4],
                                      const float* __restrict__ wp, const SMem& s,
                                      int bg, int kb, int k0) {
#pragma unroll
    for (int u = 0; u < 8; ++u) {
        wv[u] = *(const float4*)(wp + (size_t)(kb + k0 + u) * VOCAB);
#pragma unroll
        for (int bi = 0; bi < 4; ++bi) av[u][bi] = s.h2h[bg * 4 + bi][k0 + u];
    }
}

__device__ __forceinline__ void fmacg(float (&acc)[4][4], const float4 (&wv)[8],
                                      const float (&av)[8][4]) {
#pragma unroll
    for (int u = 0; u < 8; ++u) {
#pragma unroll
        for (int bi = 0; bi < 4; ++bi) {
            const float a = av[u][bi];
            acc[bi][0] = fmaf(a, wv[u].x, acc[bi][0]);
            acc[bi][1] = fmaf(a, wv[u].y, acc[bi][1]);
            acc[bi][2] = fmaf(a, wv[u].z, acc[bi][2]);
            acc[bi][3] = fmaf(a, wv[u].w, acc[bi][3]);
        }
    }
}

__device__ __forceinline__ void prologue_hg(SMem& s, int j, int tid,
                                            const float* __restrict__ U,
                                            const float* __restrict__ b_r,
                                            const float* __restrict__ hsrc,
                                            float* __restrict__ hg) {
    const int g  = j * 192 + tid;
    const int bb = (tid < 192) ? (g / G3H) : 0;
    const int c  = (tid < 192) ? (g - bb * G3H) : 0;
    float hacc = (tid < 192) ? b_r[c] : 0.f;
    for (int half = 0; half < 2; ++half) {
        const int kb = half * KH;
        __syncthreads();
        stage_half(s, hsrc, kb, tid);
        __syncthreads();
        if (tid < 192) hacc = dot256(U, s.h2h[bb], c, kb, hacc);
    }
    if (tid < 192) hg[g] = hacc;
}

__device__ __forceinline__ void phaseA(SMem& s, int j, int tid, int t,
    const float* __restrict__ U,  const float* __restrict__ b_r,
    const float* __restrict__ Wo, const float* __restrict__ bo,
    const float* __restrict__ hsrc, float* __restrict__ out,
    float* __restrict__ hg, float* __restrict__ pval, int* __restrict__ pidx)
{
    const int w   = tid >> 6;
    const int l   = tid & 63;
    const int bg  = l >> 3;
    const int cg2 = l & 7;
    const int cbase = j * CPB + w * 32 + cg2 * 4;
    const bool gemmer = (j < GEMMBLK);

    const int g     = j * 192 + tid;
    const int hb_bb = (tid < 192) ? (g / G3H) : 0;
    const int hb_c  = (tid < 192) ? (g - hb_bb * G3H) : 0;
    float hacc = (tid < 192) ? b_r[hb_c] : 0.f;

    float acc[4][4] = {};

    for (int half = 0; half < 2; ++half) {
        const int kb = half * KH;
        __syncthreads();
        stage_half(s, hsrc, kb, tid);
        __syncthreads();
        if (gemmer) {
            const float* wp = Wo + cbase;
            float4 wva[8], wvb[8];
            float  ava[8][4], avb[8][4];
            loadg(wva, ava, wp, s, bg, kb, 0);
            for (int k0 = 0; k0 < KH; k0 += 16) {
                loadg(wvb, avb, wp, s, bg, kb, k0 + 8);
                fmacg(acc, wva, ava);
                if (k0 + 16 < KH) loadg(wva, ava, wp, s, bg, kb, k0 + 16);
                fmacg(acc, wvb, avb);
            }
        }
        if (tid < 192) hacc = dot256(U, s.h2h[hb_bb], hb_c, kb, hacc);
    }

    if (tid < 192) hg[g] = hacc;

    if (gemmer) {
        const float4 bov = *(const float4*)(bo + cbase);
#pragma unroll
        for (int bi = 0; bi < 4; ++bi) {
            const int bb = bg * 4 + bi;
            float4 v;
            v.x = acc[bi][0] + bov.x;
            v.y = acc[bi][1] + bov.y;
            v.z = acc[bi][2] + bov.z;
            v.w = acc[bi][3] + bov.w;
            *(float4*)(out + ((size_t)bb * TSTEPS + t) * VOCAB + cbase) = v;

            float lv[TOPKN]; int li[TOPKN];
#pragma unroll
            for (int q = 0; q < TOPKN; ++q) { lv[q] = -INFINITY; li[q] = 0x7fffffff; }
            ins5(lv, li, v.x, cbase + 0);
            ins5(lv, li, v.y, cbase + 1);
            ins5(lv, li, v.z, cbase + 2);
            ins5(lv, li, v.w, cbase + 3);
#pragma unroll
            for (int mask = 1; mask < 8; mask <<= 1) {
                float ov[TOPKN]; int oi[TOPKN];
#pragma unroll
                for (int q = 0; q < TOPKN; ++q) {
                    ov[q] = __shfl_xor(lv[q], mask);
                    oi[q] = __shfl_xor(li[q], mask);
                }
#pragma unroll
                for (int q = 0; q < TOPKN; ++q) ins5(lv, li, ov[q], oi[q]);
            }
            if (cg2 == 0) {
#pragma unroll
                for (int q = 0; q < TOPKN; ++q) { s.mbv[w][bb][q] = lv[q]; s.mbi[w][bb][q] = li[q]; }
            }
        }
    }
    __syncthreads();
    if (gemmer && tid < BATCH) {
        float lv[TOPKN]; int li[TOPKN];
#pragma unroll
        for (int q = 0; q < TOPKN; ++q) { lv[q] = -INFINITY; li[q] = 0x7fffffff; }
#pragma unroll
        for (int w4 = 0; w4 < 4; ++w4)
#pragma unroll
            for (int q = 0; q < TOPKN; ++q) ins5(lv, li, s.mbv[w4][tid][q], s.mbi[w4][tid][q]);
        const size_t base = ((size_t)tid * NBLK + j) * TOPKN;
#pragma unroll
        for (int q = 0; q < TOPKN; ++q) { pval[base + q] = lv[q]; pidx[base + q] = li[q]; }
    }
}

__device__ __forceinline__ void phaseB(SMem& s, int j, int tid, int t,
    const float* __restrict__ E,   const float* __restrict__ Wx,
    const float* __restrict__ b_i, const int* __restrict__ rix,
    const float* __restrict__ hg,  const float* __restrict__ pval,
    const int* __restrict__ pidx,  const float* __restrict__ hcur,
    float* __restrict__ hnxt)
{
    const int bat = j >> 3;
    const int jj  = (j & 7) * 64;
    int sel = BOSTOK;
    if (t > 0) {
        float lv[TOPKN]; int li[TOPKN];
        if (tid < GEMMBLK) {
            const size_t base = ((size_t)bat * NBLK + tid) * TOPKN;
#pragma unroll
            for (int q = 0; q < TOPKN; ++q) { lv[q] = pval[base + q]; li[q] = pidx[base + q]; }
        } else {
#pragma unroll
            for (int q = 0; q < TOPKN; ++q) { lv[q] = -INFINITY; li[q] = 0x7fffffff; }
        }
        const int ridx = rix[(t - 1) * BATCH + bat];
        for (int r = 0; r < TOPKN; ++r) {
            float cv = lv[0]; int ci = li[0]; int ct = tid;
#pragma unroll
            for (int mask = 1; mask < 64; mask <<= 1) {
                const float ov = __shfl_xor(cv, mask);
                const int   oi = __shfl_xor(ci, mask);
                const int   ot = __shfl_xor(ct, mask);
                if (better(ov, oi, cv, ci)) { cv = ov; ci = oi; ct = ot; }
            }
            if ((tid & 63) == 0) { s.mrgv[tid >> 6] = cv; s.mrgi[tid >> 6] = ci; s.mrgt[tid >> 6] = ct; }
            __syncthreads();
            float bv = s.mrgv[0]; int bi_ = s.mrgi[0]; int bt = s.mrgt[0];
#pragma unroll
            for (int wq = 1; wq < 4; ++wq)
                if (better(s.mrgv[wq], s.mrgi[wq], bv, bi_)) { bv = s.mrgv[wq]; bi_ = s.mrgi[wq]; bt = s.mrgt[wq]; }
            if (r == ridx) sel = bi_;
            __syncthreads();
            if (tid == bt) {
                lv[0]=lv[1]; li[0]=li[1]; lv[1]=lv[2]; li[1]=li[2];
                lv[2]=lv[3]; li[2]=li[3]; lv[3]=lv[4]; li[3]=li[4];
                lv[4] = -INFINITY; li[4] = 0x7fffffff;
            }
        }
    }
    for (int i = tid; i < DIM; i += NTHR) {
        const float e = E[(size_t)sel * DIM + i];
        s.sx[i] = e > 0.f ? e : ALPHA * e;
    }
    __syncthreads();
    if (tid < 192) {
        const int o = tid & 63, part = tid >> 6;
        const int c = jj + o + part * HDIM;
        float a = b_i[c];
        a = dot256(Wx, s.sx, c, 0, a);
        a = dot256(Wx, s.sx + KH, c, KH, a);
        s.dd[part][o] = a;
    }
    __syncthreads();
    if (tid < 64) {
        const int c = jj + tid;
        const float xz = s.dd[0][tid], xr = s.dd[1][tid], xh = s.dd[2][tid];
        const float* hgb = hg + (size_t)bat * G3H;
        const float hz = hgb[c], hr = hgb[c + HDIM], hh = hgb[c + 2 * HDIM];
        const float z    = 1.f / (1.f + expf(-(xz + hz)));
        const float r    = 1.f / (1.f + expf(-(xr + hr)));
        const float cand = tanhf(xh + r * hh);
        const float hold = hcur[bat * HDIM + c];
        hnxt[bat * HDIM + c] = z * hold + (1.f - z) * cand;
    }
}

static __global__ void __launch_bounds__(NTHR, 1)
gru_coop(const float* __restrict__ E,  const float* __restrict__ Wx,
         const float* __restrict__ U,  const float* __restrict__ b_i,
         const float* __restrict__ b_r,const float* __restrict__ Wo,
         const float* __restrict__ bo, const float* __restrict__ ctx,
         const int* __restrict__ rix,  float* __restrict__ out,
         float* __restrict__ hbuf,     float* __restrict__ hg,
         float* __restrict__ pval,     int* __restrict__ pidx)
{
    cg::grid_group grid = cg::this_grid();
    const int j = blockIdx.x, tid = threadIdx.x;
    __shared__ SMem s;
    {
        const int g1 = j * NTHR + tid;
        if (g1 < (BATCH * HDIM) / 4) ((float4*)hbuf)[g1] = ((const float4*)ctx)[g1];
    }
    prologue_hg(s, j, tid, U, b_r, ctx, hg);
    grid.sync();
    for (int t = 0; t < TSTEPS; ++t) {
        const int p = t & 1;
        const float* hcur = hbuf + p * (BATCH * HDIM);
        float*       hnxt = hbuf + (p ^ 1) * (BATCH * HDIM);
        phaseB(s, j, tid, t, E, Wx, b_i, rix, hg, pval, pidx, hcur, hnxt);
        grid.sync();
        phaseA(s, j, tid, t, U, b_r, Wo, bo, hnxt, out, hg, pval, pidx);
        grid.sync();
    }
}

static __global__ void __launch_bounds__(NTHR, 1)
k_prologue(const float* __restrict__ U, const float* __restrict__ b_r,
           const float* __restrict__ ctx, float* __restrict__ hbuf,
           float* __restrict__ hg)
{
    __shared__ SMem s;
    const int j = blockIdx.x, tid = threadIdx.x;
    const int g1 = j * NTHR + tid;
    if (g1 < (BATCH * HDIM) / 4) ((float4*)hbuf)[g1] = ((const float4*)ctx)[g1];
    prologue_hg(s, j, tid, U, b_r, ctx, hg);
}

static __global__ void __launch_bounds__(NTHR, 1)
k_phaseB(int t, const float* __restrict__ E, const float* __restrict__ Wx,
         const float* __restrict__ b_i, const int* __restrict__ rix,
         const float* __restrict__ hg, const float* __restrict__ pval,
         const int* __restrict__ pidx, float* __restrict__ hbuf)
{
    __shared__ SMem s;
    const int p = t & 1;
    phaseB(s, blockIdx.x, threadIdx.x, t, E, Wx, b_i, rix, hg, pval, pidx,
           hbuf + p * (BATCH * HDIM), hbuf + (p ^ 1) * (BATCH * HDIM));
}

static __global__ void __launch_bounds__(NTHR, 1)
k_phaseA(int t, const float* __restrict__ U, const float* __restrict__ b_r,
         const float* __restrict__ Wo, const float* __restrict__ bo,
         const float* __restrict__ hbuf, float* __restrict__ out,
         float* __restrict__ hg, float* __restrict__ pval, int* __restrict__ pidx)
{
    __shared__ SMem s;
    const int p = t & 1;
    phaseA(s, blockIdx.x, threadIdx.x, t, U, b_r, Wo, bo,
           hbuf + (p ^ 1) * (BATCH * HDIM), out, hg, pval, pidx);
}

// =====================================================================
extern "C" void kernel_launch(void* const* d_in, const int* in_sizes, int n_in,
                              void* d_out, int out_size, void* d_ws, size_t ws_size,
                              hipStream_t stream) {
    (void)in_sizes; (void)n_in; (void)out_size;
    const float* E   = (const float*)d_in[0];
    const float* Wx  = (const float*)d_in[1];
    const float* U   = (const float*)d_in[2];
    const float* b_i = (const float*)d_in[3];
    const float* b_r = (const float*)d_in[4];
    const float* Wo  = (const float*)d_in[5];
    const float* bo  = (const float*)d_in[6];
    const float* ctx = (const float*)d_in[7];
    const int*   rix = (const int*)d_in[8];
    float* out = (float*)d_out;

    int dev = 0;
    (void)hipGetDevice(&dev);
    int coopAttr = 0, numCU = 0;
    (void)hipDeviceGetAttribute(&coopAttr, hipDeviceAttributeCooperativeLaunch, dev);
    (void)hipDeviceGetAttribute(&numCU, hipDeviceAttributeMultiprocessorCount, dev);

    // ---- round-6 ws layout (bytes, 8B aligned) ----
    const size_t oWoPk = 0;            // 512*32000*2      = 32,768,000
    const size_t oWoT  = 32768000;     // 32000*512*4      = 65,536,000
    const size_t oUT   = 98304000;     // 1536*512*4       =  3,145,728
    const size_t oWxT  = 101449728;    // 1536*512*4       =  3,145,728
    const size_t oH2X  = 104595456;    // 2*32*256*8       =    131,072
    const size_t oHG   = 104726528;    // 32*1536*4        =    196,608
    const size_t oPVX  = 104923136;    // 32*250*5*8       =    320,000
    const size_t oBAR  = 105243136;    // edge counters    =      2,048
    const size_t oSEL  = 105245184;    // selw[32]         =        128
    const size_t need  = 105245312;

    const int LDSBYTES = (int)sizeof(L6);

    bool launched = false;
    if (coopAttr && ws_size >= need) {
        (void)hipFuncSetAttribute((const void*)gru6,
                                  hipFuncAttributeMaxDynamicSharedMemorySize, LDSBYTES);
        int maxBlk = 0;
        (void)hipOccupancyMaxActiveBlocksPerMultiprocessor(&maxBlk, gru6, NTHR, LDSBYTES);
        if (maxBlk >= 1 && (long)maxBlk * numCU >= NBLK) {
            char* w = (char*)d_ws;
            unsigned* WoPk = (unsigned*)(w + oWoPk);
            float* WoT  = (float*)(w + oWoT);
            float* UT   = (float*)(w + oUT);
            float* WxT  = (float*)(w + oWxT);
            u64*   h2x  = (u64*)(w + oH2X);
            float* hg   = (float*)(w + oHG);
            u64*   pvx  = (u64*)(w + oPVX);
            unsigned* bar = (unsigned*)(w + oBAR);
            unsigned* selw = (unsigned*)(w + oSEL);
            hipError_t em = hipMemsetAsync((void*)bar, 0, 2048, stream);
            if (em == hipSuccess) {
                void* args[] = {&E, &Wx, &U, &b_i, &b_r, &Wo, &bo, &ctx, &rix, &out,
                                &WoPk, &WoT, &UT, &WxT, &h2x, &hg, &pvx, &bar, &selw};
                if (hipLaunchCooperativeKernel(gru6, dim3(NBLK), dim3(NTHR),
                                               args, (unsigned)LDSBYTES, stream) == hipSuccess)
                    launched = true;
                else (void)hipGetLastError();
            } else (void)hipGetLastError();
        }
    }

    if (!launched) {
        // ---- proven round-2 f32 path ----
        float* ws   = (float*)d_ws;
        float* hbuf = ws;
        float* hg   = ws + 32768;
        float* pval = ws + 81920;
        int*   pidx = (int*)(ws + 122880);
        bool coop_done = false;
        if (coopAttr) {
            int maxBlk = 0;
            (void)hipOccupancyMaxActiveBlocksPerMultiprocessor(&maxBlk, gru_coop, NTHR, 0);
            if (maxBlk >= 1 && (long)maxBlk * numCU >= NBLK) {
                void* args[] = {&E, &Wx, &U, &b_i, &b_r, &Wo, &bo, &ctx, &rix,
                                &out, &hbuf, &hg, &pval, &pidx};
                if (hipLaunchCooperativeKernel(gru_coop, dim3(NBLK), dim3(NTHR),
                                               args, 0u, stream) == hipSuccess) coop_done = true;
                else (void)hipGetLastError();
            }
        }
        if (!coop_done) {
            k_prologue<<<dim3(NBLK), dim3(NTHR), 0, stream>>>(U, b_r, ctx, hbuf, hg);
            for (int t = 0; t < TSTEPS; ++t) {
                k_phaseB<<<dim3(NBLK), dim3(NTHR), 0, stream>>>(t, E, Wx, b_i, rix,
                                                                hg, pval, pidx, hbuf);
                k_phaseA<<<dim3(NBLK), dim3(NTHR), 0, stream>>>(t, U, b_r, Wo, bo,
                                                                hbuf, out, hg, pval, pidx);
            }
        }
    }
}

// Round 7
// 14832.501 us; speedup vs baseline: 1.2491x; 1.2491x over previous
//
#include <hip/hip_runtime.h>

#define VOCAB   32000
#define DIM     512
#define HDIM    512
#define BATCH   32
#define TSTEPS  128
#define TOPKN   5
#define CAND    8
#define BOSTOK  1
#define ALPHA   0.2f
#define G3H     1536

#define NBLK    256
#define NTHR    256
#define GEMMBLK 250
#define CPB     128

typedef unsigned long long u64;
typedef __bf16 bf16x8 __attribute__((ext_vector_type(8)));
typedef float  f32x4  __attribute__((ext_vector_type(4)));

// ---------------- shared helpers ----------------
__device__ __forceinline__ bool better(float v1, int i1, float v2, int i2) {
    return (v1 > v2) || (v1 == v2 && i1 < i2);   // value desc, index asc
}

__device__ __forceinline__ void ins5(float (&lv)[TOPKN], int (&li)[TOPKN], float v, int i) {
    if (better(v, i, lv[4], li[4])) {
        lv[4] = v; li[4] = i;
#pragma unroll
        for (int q = 4; q > 0; --q) {
            if (better(lv[q], li[q], lv[q - 1], li[q - 1])) {
                float tv = lv[q]; lv[q] = lv[q - 1]; lv[q - 1] = tv;
                int   ti = li[q]; li[q] = li[q - 1]; li[q - 1] = ti;
            }
        }
    }
}

__device__ __forceinline__ void ins8(float (&lv)[CAND], int (&li)[CAND], float v, int i) {
    if (better(v, i, lv[CAND - 1], li[CAND - 1])) {
        lv[CAND - 1] = v; li[CAND - 1] = i;
#pragma unroll
        for (int q = CAND - 1; q > 0; --q) {
            if (better(lv[q], li[q], lv[q - 1], li[q - 1])) {
                float tv = lv[q]; lv[q] = lv[q - 1]; lv[q - 1] = tv;
                int   ti = li[q]; li[q] = li[q - 1]; li[q - 1] = ti;
            }
        }
    }
}

__device__ __forceinline__ unsigned f2bf(float f) {   // f32 -> bf16 RNE
    unsigned u = __float_as_uint(f);
    return (u + 0x7FFFu + ((u >> 16) & 1u)) >> 16;
}

// =====================================================================
// ================ round-7: multi-kernel graph path ===================
// =====================================================================

// --- prologue: build WoPk (bf16 MFMA B-frags), WoT, UT, WxT ---
static __global__ void __launch_bounds__(NTHR, 1)
kProlog(const float* __restrict__ Wo, const float* __restrict__ U,
        const float* __restrict__ Wx,
        unsigned* __restrict__ WoPk, float* __restrict__ WoT,
        float* __restrict__ UT, float* __restrict__ WxT)
{
    __shared__ float tile[64][129];
    const int j = blockIdx.x, tid = threadIdx.x;
    for (int i = tid; i < 6 * DIM; i += NTHR) {   // U_T / Wx_T rows (6 gate-cols)
        const int rr = i >> 9, k = i & 511;
        const int gc = (rr >> 1) * HDIM + 2 * j + (rr & 1);
        UT[(size_t)gc * DIM + k]  = U[(size_t)k * G3H + gc];
        WxT[(size_t)gc * DIM + k] = Wx[(size_t)k * G3H + gc];
    }
    if (j < GEMMBLK) {
        for (int chunk = 0; chunk < 8; ++chunk) {
            const int k0 = chunk * 64;
            __syncthreads();
#pragma unroll
            for (int it = 0; it < 8; ++it) {      // coalesced f32 tile [64][128]
                const int idx = tid + it * NTHR;
                const int kk = idx >> 5, c4 = (idx & 31) << 2;
                const float4 v = *(const float4*)(Wo + (size_t)(k0 + kk) * VOCAB + j * CPB + c4);
                tile[kk][c4] = v.x; tile[kk][c4 + 1] = v.y;
                tile[kk][c4 + 2] = v.z; tile[kk][c4 + 3] = v.w;
            }
            __syncthreads();
            {   // Wo_T f32 (exact, for SEL rescore)
                const int kh = tid >> 7, c = tid & 127;
                float* dst = WoT + ((size_t)j * CPB + c) * DIM + k0 + kh * 32;
#pragma unroll
                for (int kk = 0; kk < 32; ++kk) dst[kk] = tile[kh * 32 + kk][c];
            }
            // Wo packed bf16 in MFMA B-frag order (proven r3-r6)
#pragma unroll
            for (int uu = 0; uu < 4; ++uu) {
                const int u = tid + uu * NTHR;
                const int kss = u >> 9, nt = (u >> 6) & 7, ll = u & 63;
                const int kb = kss * 32 + ((ll >> 4) << 3);
                const int c  = nt * 16 + (ll & 15);
                unsigned d[4];
#pragma unroll
                for (int e2 = 0; e2 < 4; ++e2) {
                    const unsigned lo = f2bf(tile[kb + 2 * e2][c]);
                    const unsigned hi = f2bf(tile[kb + 2 * e2 + 1][c]);
                    d[e2] = lo | (hi << 16);
                }
                const int ksg = chunk * 2 + kss;
                uint4* dst = (uint4*)WoPk + ((((size_t)j * 16 + ksg) * 8 + nt) * 64 + ll);
                *dst = *(const uint4*)d;
            }
        }
    }
}

// --- hg_0 = ctx @ U + b_r (block j computes its 192-entry slice via UT) ---
static __global__ void __launch_bounds__(NTHR, 1)
kHg0(const float* __restrict__ ctx, const float* __restrict__ UT,
     const float* __restrict__ b_r, float* __restrict__ hg)
{
    const int j = blockIdx.x, tid = threadIdx.x;
    if (tid < 192) {
        const int g  = j * 192 + tid;
        const int bb = j >> 3;
        const int c  = 192 * (j & 7) + tid;
        const float4* hp = (const float4*)(ctx + (size_t)bb * HDIM);
        const float4* up = (const float4*)(UT + (size_t)c * DIM);
        float a0 = b_r[c], a1 = 0.f, a2 = 0.f, a3 = 0.f;
#pragma unroll 4
        for (int i = 0; i < 128; i += 4) {
            float4 h0 = hp[i],     u0 = up[i];
            float4 h1 = hp[i + 1], u1 = up[i + 1];
            float4 h2v = hp[i + 2], u2 = up[i + 2];
            float4 h3 = hp[i + 3], u3 = up[i + 3];
            a0 = fmaf(h0.x, u0.x, fmaf(h0.y, u0.y, fmaf(h0.z, u0.z, fmaf(h0.w, u0.w, a0))));
            a1 = fmaf(h1.x, u1.x, fmaf(h1.y, u1.y, fmaf(h1.z, u1.z, fmaf(h1.w, u1.w, a1))));
            a2 = fmaf(h2v.x, u2.x, fmaf(h2v.y, u2.y, fmaf(h2v.z, u2.z, fmaf(h2v.w, u2.w, a2))));
            a3 = fmaf(h3.x, u3.x, fmaf(h3.y, u3.y, fmaf(h3.z, u3.z, fmaf(h3.w, u3.w, a3))));
        }
        hg[g] = (a0 + a1) + (a2 + a3);
    }
}

// --- SEL: block b merges partials -> top8 -> exact rescore -> sel[b] for step t ---
static __global__ void __launch_bounds__(NTHR, 1)
kSel(int t, const float* __restrict__ WoT, const float* __restrict__ bo,
     const int* __restrict__ rix, const float* __restrict__ h2prev,
     const u64* __restrict__ pvx, unsigned* __restrict__ selw)
{
    __shared__ u64   m8[4][CAND];
    __shared__ int   c8[CAND];
    __shared__ float e8[CAND];
    const int b = blockIdx.x, tid = threadIdx.x;
    float lv[TOPKN]; int li[TOPKN];
#pragma unroll
    for (int q = 0; q < TOPKN; ++q) { lv[q] = -INFINITY; li[q] = 0x7fffffff; }
    const u64* pb = pvx + (size_t)b * (GEMMBLK * TOPKN);
    for (int e = tid; e < GEMMBLK * TOPKN; e += NTHR) {   // <=5/thread: lossless
        const u64 v = pb[e];
        ins5(lv, li, __uint_as_float((unsigned)(v >> 32)), (int)(unsigned)v);
    }
    float v8[CAND]; int i8[CAND];
#pragma unroll
    for (int q = 0; q < CAND; ++q) {
        v8[q] = (q < TOPKN) ? lv[q] : -INFINITY;
        i8[q] = (q < TOPKN) ? li[q] : 0x7fffffff;
    }
#pragma unroll
    for (int m = 1; m < 64; m <<= 1) {
#pragma unroll
        for (int q = 0; q < CAND; ++q) {
            const float ov = __shfl_xor(v8[q], m);
            const int   oi = __shfl_xor(i8[q], m);
            ins8(v8, i8, ov, oi);
        }
    }
    if ((tid & 63) == 0) {
#pragma unroll
        for (int q = 0; q < CAND; ++q)
            m8[tid >> 6][q] = ((u64)__float_as_uint(v8[q]) << 32) | (unsigned)i8[q];
    }
    __syncthreads();
    if (tid == 0) {
        float f8[CAND]; int fi[CAND];
#pragma unroll
        for (int q = 0; q < CAND; ++q) { f8[q] = -INFINITY; fi[q] = 0x7fffffff; }
#pragma unroll
        for (int w2 = 0; w2 < 4; ++w2)
#pragma unroll
            for (int q = 0; q < CAND; ++q) {
                const u64 v = m8[w2][q];
                ins8(f8, fi, __uint_as_float((unsigned)(v >> 32)), (int)(unsigned)v);
            }
#pragma unroll
        for (int q = 0; q < CAND; ++q) c8[q] = fi[q];
    }
    __syncthreads();
    {   // exact rescore: 8 groups x 32 lanes, coalesced rows
        const int gp = tid >> 5, sub = tid & 31;
        const int cnd = c8[gp];
        const float4* wp = (const float4*)(WoT + (size_t)cnd * DIM) + sub * 4;
        const float4* hp = (const float4*)(h2prev + (size_t)b * HDIM) + sub * 4;
        float a = 0.f;
#pragma unroll
        for (int ii = 0; ii < 4; ++ii) {
            const float4 wv = wp[ii], hv = hp[ii];
            a = fmaf(hv.x, wv.x, fmaf(hv.y, wv.y, fmaf(hv.z, wv.z, fmaf(hv.w, wv.w, a))));
        }
#pragma unroll
        for (int m = 1; m < 32; m <<= 1) a += __shfl_xor(a, m);
        if (sub == 0) e8[gp] = a + bo[cnd];
    }
    __syncthreads();
    if (tid == 0) {
        float lv5[TOPKN]; int li5[TOPKN];
#pragma unroll
        for (int q = 0; q < TOPKN; ++q) { lv5[q] = -INFINITY; li5[q] = 0x7fffffff; }
#pragma unroll
        for (int q = 0; q < CAND; ++q) ins5(lv5, li5, e8[q], c8[q]);
        const int ridx = rix[(t - 1) * BATCH + b];
        int sb = li5[0];
#pragma unroll
        for (int q = 1; q < TOPKN; ++q) if (ridx == q) sb = li5[q];
        selw[b] = (unsigned)sb;
    }
}

// --- GATE: block j -> hcols {2j,2j+1}: E-stage, xg dots, GRU update -> h2cur ---
struct GateLDS {
    float er[BATCH][516];   // leaky(E[sel]) rows (stride 516: bank spread)  66 KB
    float xgs[BATCH][6];
    int   sel[BATCH];
};

static __global__ void __launch_bounds__(NTHR, 1)
kGate(int t, const float* __restrict__ E, const float* __restrict__ WxT,
      const float* __restrict__ b_i, const float* __restrict__ ctx,
      const unsigned* __restrict__ selw, const float* __restrict__ hg,
      const float* __restrict__ h2prev, float* __restrict__ h2cur)
{
    extern __shared__ char raw[];
    GateLDS& s = *(GateLDS*)raw;
    const int j = blockIdx.x, tid = threadIdx.x;
    if (tid < BATCH)
        s.sel[tid] = (t == 0) ? BOSTOK : (int)selw[tid];
    __syncthreads();
    {   // stage leaky(E[sel[b]]): 8 threads x 16 float4 per row
        const int b = tid >> 3, ch = tid & 7;
        const float4* src = (const float4*)(E + (size_t)s.sel[b] * DIM) + ch * 16;
        float* dst = &s.er[b][ch * 64];
#pragma unroll
        for (int i = 0; i < 16; ++i) {
            float4 v = src[i];
            v.x = v.x > 0.f ? v.x : ALPHA * v.x;
            v.y = v.y > 0.f ? v.y : ALPHA * v.y;
            v.z = v.z > 0.f ? v.z : ALPHA * v.z;
            v.w = v.w > 0.f ? v.w : ALPHA * v.w;
            *(float4*)(dst + 4 * i) = v;
        }
    }
    __syncthreads();
    if (tid < 192) {   // xg dots: (bb, pp) -> gate-col gc; WxT row broadcast over 32 lanes
        const int bb = tid & 31, pp = tid >> 5;
        const int gc = (pp >> 1) * HDIM + 2 * j + (pp & 1);
        const float4* er = (const float4*)&s.er[bb][0];
        const float4* wx = (const float4*)(WxT + (size_t)gc * DIM);
        float a0 = b_i[gc], a1 = 0.f, a2 = 0.f, a3 = 0.f;
#pragma unroll 4
        for (int i = 0; i < 128; i += 4) {
            const float4 e0 = er[i],     w0 = wx[i];
            const float4 e1 = er[i + 1], w1 = wx[i + 1];
            const float4 e2 = er[i + 2], w2 = wx[i + 2];
            const float4 e3 = er[i + 3], w3 = wx[i + 3];
            a0 = fmaf(e0.x, w0.x, fmaf(e0.y, w0.y, fmaf(e0.z, w0.z, fmaf(e0.w, w0.w, a0))));
            a1 = fmaf(e1.x, w1.x, fmaf(e1.y, w1.y, fmaf(e1.z, w1.z, fmaf(e1.w, w1.w, a1))));
            a2 = fmaf(e2.x, w2.x, fmaf(e2.y, w2.y, fmaf(e2.z, w2.z, fmaf(e2.w, w2.w, a2))));
            a3 = fmaf(e3.x, w3.x, fmaf(e3.y, w3.y, fmaf(e3.z, w3.z, fmaf(e3.w, w3.w, a3))));
        }
        s.xgs[bb][pp] = (a0 + a1) + (a2 + a3);
    }
    __syncthreads();
    if (tid < 64) {   // GRU update: (bb, q) -> hcol 2j+q
        const int bb = tid >> 1, q = tid & 1, hc = 2 * j + q;
        const float hold = (t == 0) ? ctx[(size_t)bb * HDIM + hc]
                                    : h2prev[(size_t)bb * HDIM + hc];
        const float xz = s.xgs[bb][q], xr = s.xgs[bb][2 + q], xh = s.xgs[bb][4 + q];
        const float hz  = hg[(size_t)bb * G3H + hc];
        const float hr_ = hg[(size_t)bb * G3H + HDIM + hc];
        const float hh  = hg[(size_t)bb * G3H + 2 * HDIM + hc];
        const float z  = 1.f / (1.f + expf(-(xz + hz)));
        const float r  = 1.f / (1.f + expf(-(xr + hr_)));
        const float cd = tanhf(xh + r * hh);
        h2cur[(size_t)bb * HDIM + hc] = z * hold + (1.f - z) * cd;
    }
}

// --- GEMM: stage h2 -> LDS (f32 + swz bf16), MFMA logits, topk partials, hg_{t+1} ---
struct GemmLDS {
    u64      h2r[BATCH][256];     // raw h2 (f32 pairs)   64 KB
    unsigned hbf[BATCH][256];     // bf16-packed, XOR-swz 32 KB
    float pwv[4][BATCH][TOPKN];
    int   pwi[4][BATCH][TOPKN];
};

static __global__ void __launch_bounds__(NTHR, 1)
kGemm(int t, const unsigned* __restrict__ WoPk, const float* __restrict__ bo,
      const float* __restrict__ UT, const float* __restrict__ b_r,
      const float* __restrict__ h2in, float* __restrict__ out,
      float* __restrict__ hg, u64* __restrict__ pvx)
{
    extern __shared__ char raw[];
    GemmLDS& s = *(GemmLDS*)raw;
    const int j = blockIdx.x, tid = threadIdx.x;
#pragma unroll 4
    for (int q = 0; q < BATCH; ++q) {
        const float2 v = *(const float2*)&h2in[(size_t)q * HDIM + 2 * tid];
        s.h2r[q][tid] = __builtin_bit_cast(u64, v);
        s.hbf[q][tid ^ ((q & 7) << 2)] = f2bf(v.x) | (f2bf(v.y) << 16);  // XOR-swz
    }
    __syncthreads();
    const int w = tid >> 6, l = tid & 63;
    if (j < GEMMBLK) {
        f32x4 acc[2][2];
        acc[0][0] = {0.f,0.f,0.f,0.f}; acc[0][1] = {0.f,0.f,0.f,0.f};
        acc[1][0] = {0.f,0.f,0.f,0.f}; acc[1][1] = {0.f,0.f,0.f,0.f};
        const uint4* wpk = (const uint4*)WoPk;
        const size_t base = (size_t)j * 8192 + l;
        const int r0 = l & 15, r1 = 16 + (l & 15);
        const int ko = (l >> 4) << 2;
        const int swz = (r0 & 7) << 2;
        uint4 vb[8];
#pragma unroll
        for (int pf = 0; pf < 4; ++pf) {           // depth-4 prefetch
            vb[2*pf]   = wpk[base + (size_t)(pf * 8 + 2 * w)     * 64];
            vb[2*pf+1] = wpk[base + (size_t)(pf * 8 + 2 * w + 1) * 64];
        }
#pragma unroll
        for (int ks = 0; ks < 16; ++ks) {
            const int sl2 = (ks & 3) * 2;
            const uint4 b0 = vb[sl2], b1 = vb[sl2 + 1];
            const uint4 a0 = *(const uint4*)&s.hbf[r0][(ks * 16 + ko) ^ swz];
            const uint4 a1 = *(const uint4*)&s.hbf[r1][(ks * 16 + ko) ^ swz];
            if (ks < 12) {
                vb[sl2]     = wpk[base + (size_t)((ks + 4) * 8 + 2 * w)     * 64];
                vb[sl2 + 1] = wpk[base + (size_t)((ks + 4) * 8 + 2 * w + 1) * 64];
            }
            const bf16x8 A0 = __builtin_bit_cast(bf16x8, a0);
            const bf16x8 A1 = __builtin_bit_cast(bf16x8, a1);
            const bf16x8 B0 = __builtin_bit_cast(bf16x8, b0);
            const bf16x8 B1 = __builtin_bit_cast(bf16x8, b1);
            acc[0][0] = __builtin_amdgcn_mfma_f32_16x16x32_bf16(A0, B0, acc[0][0], 0, 0, 0);
            acc[0][1] = __builtin_amdgcn_mfma_f32_16x16x32_bf16(A0, B1, acc[0][1], 0, 0, 0);
            acc[1][0] = __builtin_amdgcn_mfma_f32_16x16x32_bf16(A1, B0, acc[1][0], 0, 0, 0);
            acc[1][1] = __builtin_amdgcn_mfma_f32_16x16x32_bf16(A1, B1, acc[1][1], 0, 0, 0);
        }
        const int c0 = j * CPB + (2 * w) * 16 + (l & 15);
        const int c1 = j * CPB + (2 * w + 1) * 16 + (l & 15);
        const float bo0 = bo[c0], bo1 = bo[c1];
#pragma unroll
        for (int m = 0; m < 2; ++m) {
#pragma unroll
            for (int r = 0; r < 4; ++r) {
                const int b = 16 * m + ((l >> 4) << 2) + r;
                const float v0 = acc[m][0][r] + bo0;
                const float v1 = acc[m][1][r] + bo1;
                __builtin_nontemporal_store(v0, out + ((size_t)b * TSTEPS + t) * VOCAB + c0);
                __builtin_nontemporal_store(v1, out + ((size_t)b * TSTEPS + t) * VOCAB + c1);
                float lv[TOPKN]; int li[TOPKN];
#pragma unroll
                for (int q = 0; q < TOPKN; ++q) { lv[q] = -INFINITY; li[q] = 0x7fffffff; }
                ins5(lv, li, v0, c0);
                ins5(lv, li, v1, c1);
#pragma unroll
                for (int mask = 1; mask < 16; mask <<= 1) {
                    float ov[TOPKN]; int oi[TOPKN];
#pragma unroll
                    for (int q = 0; q < TOPKN; ++q) {
                        ov[q] = __shfl_xor(lv[q], mask);
                        oi[q] = __shfl_xor(li[q], mask);
                    }
#pragma unroll
                    for (int q = 0; q < TOPKN; ++q) ins5(lv, li, ov[q], oi[q]);
                }
                if ((l & 15) == 0) {
#pragma unroll
                    for (int q = 0; q < TOPKN; ++q) { s.pwv[w][b][q] = lv[q]; s.pwi[w][b][q] = li[q]; }
                }
            }
        }
    }
    // hg_{t+1} from LDS-staged h2 (broadcast reads, per-lane UT rows)
    if (tid < 192) {
        const int g  = j * 192 + tid;
        const int bb = j >> 3;
        const int c  = 192 * (j & 7) + tid;
        const float4* hr = (const float4*)&s.h2r[bb][0];
        const float4* up = (const float4*)(UT + (size_t)c * DIM);
        float a0 = b_r[c], a1 = 0.f, a2 = 0.f, a3 = 0.f;
#pragma unroll 4
        for (int i = 0; i < 128; i += 4) {
            const float4 u0 = up[i],     h0 = hr[i];
            const float4 u1 = up[i + 1], h1 = hr[i + 1];
            const float4 u2 = up[i + 2], h2v = hr[i + 2];
            const float4 u3 = up[i + 3], h3 = hr[i + 3];
            a0 = fmaf(h0.x, u0.x, fmaf(h0.y, u0.y, fmaf(h0.z, u0.z, fmaf(h0.w, u0.w, a0))));
            a1 = fmaf(h1.x, u1.x, fmaf(h1.y, u1.y, fmaf(h1.z, u1.z, fmaf(h1.w, u1.w, a1))));
            a2 = fmaf(h2v.x, u2.x, fmaf(h2v.y, u2.y, fmaf(h2v.z, u2.z, fmaf(h2v.w, u2.w, a2))));
            a3 = fmaf(h3.x, u3.x, fmaf(h3.y, u3.y, fmaf(h3.z, u3.z, fmaf(h3.w, u3.w, a3))));
        }
        hg[g] = (a0 + a1) + (a2 + a3);
    }
    __syncthreads();
    if (j < GEMMBLK && tid < BATCH) {
        float lv[TOPKN]; int li[TOPKN];
#pragma unroll
        for (int q = 0; q < TOPKN; ++q) { lv[q] = -INFINITY; li[q] = 0x7fffffff; }
#pragma unroll
        for (int w4 = 0; w4 < 4; ++w4)
#pragma unroll
            for (int q = 0; q < TOPKN; ++q) ins5(lv, li, s.pwv[w4][tid][q], s.pwi[w4][tid][q]);
        const size_t base = ((size_t)tid * GEMMBLK + j) * TOPKN;
#pragma unroll
        for (int q = 0; q < TOPKN; ++q)
            pvx[base + q] = ((u64)__float_as_uint(lv[q]) << 32) | (unsigned)li[q];
    }
}

// =====================================================================
// ================= round-2 f32 fallback (proven) =====================
// =====================================================================

#define KH      256
#define H2LD    (KH + 1)

struct alignas(16) SMem {
    float h2h[BATCH][H2LD];
    float sx[DIM];
    float dd[3][64];
    float mbv[4][BATCH][TOPKN];
    int   mbi[4][BATCH][TOPKN];
    float mrgv[4];
    int   mrgi[4];
    int   mrgt[4];
};

__device__ __forceinline__ float dot256(const float* __restrict__ M, const float* sv,
                                        int c, int kb, float acc) {
    const float* p = M + (size_t)kb * G3H + c;
    float wa[32], wb[32];
#pragma unroll
    for (int u = 0; u < 32; ++u) wa[u] = p[(size_t)u * G3H];
    for (int k0 = 0; k0 < KH; k0 += 64) {
#pragma unroll
        for (int u = 0; u < 32; ++u) wb[u] = p[(size_t)(k0 + 32 + u) * G3H];
#pragma unroll
        for (int u = 0; u < 32; ++u) acc = fmaf(sv[k0 + u], wa[u], acc);
        if (k0 + 64 < KH) {
#pragma unroll
            for (int u = 0; u < 32; ++u) wa[u] = p[(size_t)(k0 + 64 + u) * G3H];
        }
#pragma unroll
        for (int u = 0; u < 32; ++u) acc = fmaf(sv[k0 + 32 + u], wb[u], acc);
    }
    return acc;
}

__device__ __forceinline__ void stage_half(SMem& s, const float* __restrict__ src,
                                           int kb, int tid) {
#pragma unroll
    for (int it = 0; it < 8; ++it) {
        const int i  = tid + it * NTHR;
        const int bb = i >> 6;
        const int k4 = i & 63;
        const float4 v = *(const float4*)(src + (size_t)bb * DIM + kb + k4 * 4);
        float* d = &s.h2h[bb][k4 * 4];
        d[0] = v.x; d[1] = v.y; d[2] = v.z; d[3] = v.w;
    }
}

__device__ __forceinline__ void loadg(float4 (&wv)[8], float (&av)[8][4],
                                      const float* __restrict__ wp, const SMem& s,
                                      int bg, int kb, int k0) {
#pragma unroll
    for (int u = 0; u < 8; ++u) {
        wv[u] = *(const float4*)(wp + (size_t)(kb + k0 + u) * VOCAB);
#pragma unroll
        for (int bi = 0; bi < 4; ++bi) av[u][bi] = s.h2h[bg * 4 + bi][k0 + u];
    }
}

__device__ __forceinline__ void fmacg(float (&acc)[4][4], const float4 (&wv)[8],
                                      const float (&av)[8][4]) {
#pragma unroll
    for (int u = 0; u < 8; ++u) {
#pragma unroll
        for (int bi = 0; bi < 4; ++bi) {
            const float a = av[u][bi];
            acc[bi][0] = fmaf(a, wv[u].x, acc[bi][0]);
            acc[bi][1] = fmaf(a, wv[u].y, acc[bi][1]);
            acc[bi][2] = fmaf(a, wv[u].z, acc[bi][2]);
            acc[bi][3] = fmaf(a, wv[u].w, acc[bi][3]);
        }
    }
}

__device__ __forceinline__ void prologue_hg(SMem& s, int j, int tid,
                                            const float* __restrict__ U,
                                            const float* __restrict__ b_r,
                                            const float* __restrict__ hsrc,
                                            float* __restrict__ hg) {
    const int g  = j * 192 + tid;
    const int bb = (tid < 192) ? (g / G3H) : 0;
    const int c  = (tid < 192) ? (g - bb * G3H) : 0;
    float hacc = (tid < 192) ? b_r[c] : 0.f;
    for (int half = 0; half < 2; ++half) {
        const int kb = half * KH;
        __syncthreads();
        stage_half(s, hsrc, kb, tid);
        __syncthreads();
        if (tid < 192) hacc = dot256(U, s.h2h[bb], c, kb, hacc);
    }
    if (tid < 192) hg[g] = hacc;
}

__device__ __forceinline__ void phaseA(SMem& s, int j, int tid, int t,
    const float* __restrict__ U,  const float* __restrict__ b_r,
    const float* __restrict__ Wo, const float* __restrict__ bo,
    const float* __restrict__ hsrc, float* __restrict__ out,
    float* __restrict__ hg, float* __restrict__ pval, int* __restrict__ pidx)
{
    const int w   = tid >> 6;
    const int l   = tid & 63;
    const int bg  = l >> 3;
    const int cg2 = l & 7;
    const int cbase = j * CPB + w * 32 + cg2 * 4;
    const bool gemmer = (j < GEMMBLK);

    const int g     = j * 192 + tid;
    const int hb_bb = (tid < 192) ? (g / G3H) : 0;
    const int hb_c  = (tid < 192) ? (g - hb_bb * G3H) : 0;
    float hacc = (tid < 192) ? b_r[hb_c] : 0.f;

    float acc[4][4] = {};

    for (int half = 0; half < 2; ++half) {
        const int kb = half * KH;
        __syncthreads();
        stage_half(s, hsrc, kb, tid);
        __syncthreads();
        if (gemmer) {
            const float* wp = Wo + cbase;
            float4 wva[8], wvb[8];
            float  ava[8][4], avb[8][4];
            loadg(wva, ava, wp, s, bg, kb, 0);
            for (int k0 = 0; k0 < KH; k0 += 16) {
                loadg(wvb, avb, wp, s, bg, kb, k0 + 8);
                fmacg(acc, wva, ava);
                if (k0 + 16 < KH) loadg(wva, ava, wp, s, bg, kb, k0 + 16);
                fmacg(acc, wvb, avb);
            }
        }
        if (tid < 192) hacc = dot256(U, s.h2h[hb_bb], hb_c, kb, hacc);
    }

    if (tid < 192) hg[g] = hacc;

    if (gemmer) {
        const float4 bov = *(const float4*)(bo + cbase);
#pragma unroll
        for (int bi = 0; bi < 4; ++bi) {
            const int bb = bg * 4 + bi;
            float4 v;
            v.x = acc[bi][0] + bov.x;
            v.y = acc[bi][1] + bov.y;
            v.z = acc[bi][2] + bov.z;
            v.w = acc[bi][3] + bov.w;
            *(float4*)(out + ((size_t)bb * TSTEPS + t) * VOCAB + cbase) = v;

            float lv[TOPKN]; int li[TOPKN];
#pragma unroll
            for (int q = 0; q < TOPKN; ++q) { lv[q] = -INFINITY; li[q] = 0x7fffffff; }
            ins5(lv, li, v.x, cbase + 0);
            ins5(lv, li, v.y, cbase + 1);
            ins5(lv, li, v.z, cbase + 2);
            ins5(lv, li, v.w, cbase + 3);
#pragma unroll
            for (int mask = 1; mask < 8; mask <<= 1) {
                float ov[TOPKN]; int oi[TOPKN];
#pragma unroll
                for (int q = 0; q < TOPKN; ++q) {
                    ov[q] = __shfl_xor(lv[q], mask);
                    oi[q] = __shfl_xor(li[q], mask);
                }
#pragma unroll
                for (int q = 0; q < TOPKN; ++q) ins5(lv, li, ov[q], oi[q]);
            }
            if (cg2 == 0) {
#pragma unroll
                for (int q = 0; q < TOPKN; ++q) { s.mbv[w][bb][q] = lv[q]; s.mbi[w][bb][q] = li[q]; }
            }
        }
    }
    __syncthreads();
    if (gemmer && tid < BATCH) {
        float lv[TOPKN]; int li[TOPKN];
#pragma unroll
        for (int q = 0; q < TOPKN; ++q) { lv[q] = -INFINITY; li[q] = 0x7fffffff; }
#pragma unroll
        for (int w4 = 0; w4 < 4; ++w4)
#pragma unroll
            for (int q = 0; q < TOPKN; ++q) ins5(lv, li, s.mbv[w4][tid][q], s.mbi[w4][tid][q]);
        const size_t base = ((size_t)tid * NBLK + j) * TOPKN;
#pragma unroll
        for (int q = 0; q < TOPKN; ++q) { pval[base + q] = lv[q]; pidx[base + q] = li[q]; }
    }
}

__device__ __forceinline__ void phaseB(SMem& s, int j, int tid, int t,
    const float* __restrict__ E,   const float* __restrict__ Wx,
    const float* __restrict__ b_i, const int* __restrict__ rix,
    const float* __restrict__ hg,  const float* __restrict__ pval,
    const int* __restrict__ pidx,  const float* __restrict__ hcur,
    float* __restrict__ hnxt)
{
    const int bat = j >> 3;
    const int jj  = (j & 7) * 64;
    int sel = BOSTOK;
    if (t > 0) {
        float lv[TOPKN]; int li[TOPKN];
        if (tid < GEMMBLK) {
            const size_t base = ((size_t)bat * NBLK + tid) * TOPKN;
#pragma unroll
            for (int q = 0; q < TOPKN; ++q) { lv[q] = pval[base + q]; li[q] = pidx[base + q]; }
        } else {
#pragma unroll
            for (int q = 0; q < TOPKN; ++q) { lv[q] = -INFINITY; li[q] = 0x7fffffff; }
        }
        const int ridx = rix[(t - 1) * BATCH + bat];
        for (int r = 0; r < TOPKN; ++r) {
            float cv = lv[0]; int ci = li[0]; int ct = tid;
#pragma unroll
            for (int mask = 1; mask < 64; mask <<= 1) {
                const float ov = __shfl_xor(cv, mask);
                const int   oi = __shfl_xor(ci, mask);
                const int   ot = __shfl_xor(ct, mask);
                if (better(ov, oi, cv, ci)) { cv = ov; ci = oi; ct = ot; }
            }
            if ((tid & 63) == 0) { s.mrgv[tid >> 6] = cv; s.mrgi[tid >> 6] = ci; s.mrgt[tid >> 6] = ct; }
            __syncthreads();
            float bv = s.mrgv[0]; int bi_ = s.mrgi[0]; int bt = s.mrgt[0];
#pragma unroll
            for (int wq = 1; wq < 4; ++wq)
                if (better(s.mrgv[wq], s.mrgi[wq], bv, bi_)) { bv = s.mrgv[wq]; bi_ = s.mrgi[wq]; bt = s.mrgt[wq]; }
            if (r == ridx) sel = bi_;
            __syncthreads();
            if (tid == bt) {
                lv[0]=lv[1]; li[0]=li[1]; lv[1]=lv[2]; li[1]=li[2];
                lv[2]=lv[3]; li[2]=li[3]; lv[3]=lv[4]; li[3]=li[4];
                lv[4] = -INFINITY; li[4] = 0x7fffffff;
            }
        }
    }
    for (int i = tid; i < DIM; i += NTHR) {
        const float e = E[(size_t)sel * DIM + i];
        s.sx[i] = e > 0.f ? e : ALPHA * e;
    }
    __syncthreads();
    if (tid < 192) {
        const int o = tid & 63, part = tid >> 6;
        const int c = jj + o + part * HDIM;
        float a = b_i[c];
        a = dot256(Wx, s.sx, c, 0, a);
        a = dot256(Wx, s.sx + KH, c, KH, a);
        s.dd[part][o] = a;
    }
    __syncthreads();
    if (tid < 64) {
        const int c = jj + tid;
        const float xz = s.dd[0][tid], xr = s.dd[1][tid], xh = s.dd[2][tid];
        const float* hgb = hg + (size_t)bat * G3H;
        const float hz = hgb[c], hr = hgb[c + HDIM], hh = hgb[c + 2 * HDIM];
        const float z    = 1.f / (1.f + expf(-(xz + hz)));
        const float r    = 1.f / (1.f + expf(-(xr + hr)));
        const float cand = tanhf(xh + r * hh);
        const float hold = hcur[bat * HDIM + c];
        hnxt[bat * HDIM + c] = z * hold + (1.f - z) * cand;
    }
}

static __global__ void __launch_bounds__(NTHR, 1)
k_prologue(const float* __restrict__ U, const float* __restrict__ b_r,
           const float* __restrict__ ctx, float* __restrict__ hbuf,
           float* __restrict__ hg)
{
    __shared__ SMem s;
    const int j = blockIdx.x, tid = threadIdx.x;
    const int g1 = j * NTHR + tid;
    if (g1 < (BATCH * HDIM) / 4) ((float4*)hbuf)[g1] = ((const float4*)ctx)[g1];
    prologue_hg(s, j, tid, U, b_r, ctx, hg);
}

static __global__ void __launch_bounds__(NTHR, 1)
k_phaseB(int t, const float* __restrict__ E, const float* __restrict__ Wx,
         const float* __restrict__ b_i, const int* __restrict__ rix,
         const float* __restrict__ hg, const float* __restrict__ pval,
         const int* __restrict__ pidx, float* __restrict__ hbuf)
{
    __shared__ SMem s;
    const int p = t & 1;
    phaseB(s, blockIdx.x, threadIdx.x, t, E, Wx, b_i, rix, hg, pval, pidx,
           hbuf + p * (BATCH * HDIM), hbuf + (p ^ 1) * (BATCH * HDIM));
}

static __global__ void __launch_bounds__(NTHR, 1)
k_phaseA(int t, const float* __restrict__ U, const float* __restrict__ b_r,
         const float* __restrict__ Wo, const float* __restrict__ bo,
         const float* __restrict__ hbuf, float* __restrict__ out,
         float* __restrict__ hg, float* __restrict__ pval, int* __restrict__ pidx)
{
    __shared__ SMem s;
    const int p = t & 1;
    phaseA(s, blockIdx.x, threadIdx.x, t, U, b_r, Wo, bo,
           hbuf + (p ^ 1) * (BATCH * HDIM), out, hg, pval, pidx);
}

// =====================================================================
extern "C" void kernel_launch(void* const* d_in, const int* in_sizes, int n_in,
                              void* d_out, int out_size, void* d_ws, size_t ws_size,
                              hipStream_t stream) {
    (void)in_sizes; (void)n_in; (void)out_size;
    const float* E   = (const float*)d_in[0];
    const float* Wx  = (const float*)d_in[1];
    const float* U   = (const float*)d_in[2];
    const float* b_i = (const float*)d_in[3];
    const float* b_r = (const float*)d_in[4];
    const float* Wo  = (const float*)d_in[5];
    const float* bo  = (const float*)d_in[6];
    const float* ctx = (const float*)d_in[7];
    const int*   rix = (const int*)d_in[8];
    float* out = (float*)d_out;

    // ---- round-7 ws layout (bytes, 8B aligned) ----
    const size_t oWoPk = 0;            // 512*32000*2      = 32,768,000
    const size_t oWoT  = 32768000;     // 32000*512*4      = 65,536,000
    const size_t oUT   = 98304000;     // 1536*512*4       =  3,145,728
    const size_t oWxT  = 101449728;    // 1536*512*4       =  3,145,728
    const size_t oH2X  = 104595456;    // 2*32*512*4       =    131,072
    const size_t oHG   = 104726528;    // 32*1536*4        =    196,608
    const size_t oPVX  = 104923136;    // 32*250*5*8       =    320,000
    const size_t oSEL  = 105243136;    // selw[32]         =        128
    const size_t need  = 105243264;

    if (ws_size >= need) {
        char* w = (char*)d_ws;
        unsigned* WoPk = (unsigned*)(w + oWoPk);
        float* WoT  = (float*)(w + oWoT);
        float* UT   = (float*)(w + oUT);
        float* WxT  = (float*)(w + oWxT);
        float* h2x  = (float*)(w + oH2X);
        float* hg   = (float*)(w + oHG);
        u64*   pvx  = (u64*)(w + oPVX);
        unsigned* selw = (unsigned*)(w + oSEL);

        const int GATE_LDS = (int)sizeof(GateLDS);
        const int GEMM_LDS = (int)sizeof(GemmLDS);
        (void)hipFuncSetAttribute((const void*)kGate,
                                  hipFuncAttributeMaxDynamicSharedMemorySize, GATE_LDS);
        (void)hipFuncSetAttribute((const void*)kGemm,
                                  hipFuncAttributeMaxDynamicSharedMemorySize, GEMM_LDS);

        kProlog<<<dim3(NBLK), dim3(NTHR), 0, stream>>>(Wo, U, Wx, WoPk, WoT, UT, WxT);
        kHg0<<<dim3(NBLK), dim3(NTHR), 0, stream>>>(ctx, UT, b_r, hg);
        for (int t = 0; t < TSTEPS; ++t) {
            float*       h2cur  = h2x + (t & 1) * (BATCH * HDIM);
            const float* h2prev = h2x + ((t & 1) ^ 1) * (BATCH * HDIM);
            if (t > 0)
                kSel<<<dim3(BATCH), dim3(NTHR), 0, stream>>>(t, WoT, bo, rix,
                                                             h2prev, pvx, selw);
            kGate<<<dim3(NBLK), dim3(NTHR), GATE_LDS, stream>>>(t, E, WxT, b_i, ctx,
                                                                selw, hg, h2prev, h2cur);
            kGemm<<<dim3(NBLK), dim3(NTHR), GEMM_LDS, stream>>>(t, WoPk, bo, UT, b_r,
                                                                h2cur, out, hg, pvx);
        }
    } else {
        // ---- proven round-2 f32 multi-kernel fallback ----
        float* ws   = (float*)d_ws;
        float* hbuf = ws;
        float* hg   = ws + 32768;
        float* pval = ws + 81920;
        int*   pidx = (int*)(ws + 122880);
        k_prologue<<<dim3(NBLK), dim3(NTHR), 0, stream>>>(U, b_r, ctx, hbuf, hg);
        for (int t = 0; t < TSTEPS; ++t) {
            k_phaseB<<<dim3(NBLK), dim3(NTHR), 0, stream>>>(t, E, Wx, b_i, rix,
                                                            hg, pval, pidx, hbuf);
            k_phaseA<<<dim3(NBLK), dim3(NTHR), 0, stream>>>(t, U, b_r, Wo, bo,
                                                            hbuf, out, hg, pval, pidx);
        }
    }
}